// Round 4
// baseline (330.760 us; speedup 1.0000x reference)
//
#include <hip/hip_runtime.h>
#include <math.h>

#define SAMPLE_THRESH 0.05f

typedef float f32x4 __attribute__((ext_vector_type(4)));

// Bit-exact squared distance: explicit *_rn intrinsics are contraction
// barriers, so every kernel computes the identical fp32 bit pattern.
__device__ __forceinline__ float d2_exact(float xa0, float xa1, float a2,
                                          float xb0, float xb1, float b2) {
    float p  = __fmul_rn(xa1, xb1);
    float q  = __fmaf_rn(xa0, xb0, p);      // dot(xa, xb)
    float s  = __fadd_rn(a2, b2);
    return __fmaf_rn(-2.0f, q, s);          // a2 + b2 - 2*dot
}

// The reference's D = sqrt(max(d2, 1e-12)), correctly rounded => monotone.
__device__ __forceinline__ float f_D(float d2) {
    return __fsqrt_rn(fmaxf(d2, 1e-12f));
}

__device__ __forceinline__ float nextf_pos(float x) {  // x > 0 assumed
    return __int_as_float(__float_as_int(x) + 1);
}
__device__ __forceinline__ float prevf_pos(float x) {
    return __int_as_float(__float_as_int(x) - 1);
}

// Largest fp32 x with f_D(x) == f_D(m). Since f_D is monotone and every
// in-row d2 >= m, the mask test (D == Dmin) becomes (d2 <= hi). The scan
// starts at t*t (within ~2 ulp of the boundary) so each loop runs <=3 steps.
__device__ __forceinline__ float hi_thresh(float m) {
    float t = f_D(m);
    float x = fmaxf(m, __fmul_rn(t, t));    // positive: t >= 1e-6
    while (f_D(x) > t) x = prevf_pos(x);
    while (f_D(nextf_pos(x)) <= t) x = nextf_pos(x);
    return x;
}

// Kernel A: grid_sample (bilinear, zeros, align_corners=False) of the flow
// channels (warp[...,2], warp[...,3]) and certainty at x_A.
// Apack[i] = (fx, fy, a2, cert);  Bpack[j] = (bx, by, b2, 0)
__global__ __launch_bounds__(256) void sample_kernel(
    const float* __restrict__ xA, const float* __restrict__ xB,
    const float4* __restrict__ warp, const float* __restrict__ cert,
    float4* __restrict__ Apack, float4* __restrict__ Bpack,
    int nA, int nB, int H, int W) {
    int i = blockIdx.x * blockDim.x + threadIdx.x;
    if (i < nA) {
        float px = xA[2 * i + 0], py = xA[2 * i + 1];
        float xf = (px + 1.0f) * (0.5f * (float)W) - 0.5f;
        float yf = (py + 1.0f) * (0.5f * (float)H) - 0.5f;
        float x0f = floorf(xf), y0f = floorf(yf);
        float wx1 = xf - x0f, wy1 = yf - y0f;
        float wx0 = 1.0f - wx1, wy0 = 1.0f - wy1;
        int x0 = (int)x0f, y0 = (int)y0f;
        float fx = 0.0f, fy = 0.0f, cv = 0.0f;
#pragma unroll
        for (int dy = 0; dy < 2; ++dy) {
#pragma unroll
            for (int dx = 0; dx < 2; ++dx) {
                int xi = x0 + dx, yi = y0 + dy;
                float vm = (xi >= 0 && xi < W && yi >= 0 && yi < H) ? 1.0f : 0.0f;
                int xc = min(max(xi, 0), W - 1);
                int yc = min(max(yi, 0), H - 1);
                int idx = yc * W + xc;
                float4 wv = warp[idx];
                float  c  = cert[idx];
                float wgt = (dx ? wx1 : wx0) * (dy ? wy1 : wy0);
                fx += (wv.z * vm) * wgt;
                fy += (wv.w * vm) * wgt;
                cv += (c    * vm) * wgt;
            }
        }
        float a2 = fx * fx + fy * fy;
        Apack[i] = make_float4(fx, fy, a2, cv);
    }
    if (i < nB) {
        float b0 = xB[2 * i + 0], b1 = xB[2 * i + 1];
        Bpack[i] = make_float4(b0, b1, b0 * b0 + b1 * b1, 0.0f);
    }
}

// Fused row-min + col-min over d2 (sqrt hoisted; 8 rows/cols per wave to
// halve streamed traffic). Outputs:
//  rowpack[i] = (xa0, xa1, a2, hiRow)  hiRow = -1e30 if cert fails
//  rowD[i]    = DminRow (the output value where the mask fires)
//  colpack[j] = (xb0, xb1, b2, hiCol)
__global__ __launch_bounds__(256) void min_kernel(
    const float4* __restrict__ Apack, const float4* __restrict__ Bpack,
    float4* __restrict__ rowpack, float* __restrict__ rowD,
    float4* __restrict__ colpack, int nA, int nB) {
    int gwave = (int)((blockIdx.x * blockDim.x + threadIdx.x) >> 6);
    int lane = threadIdx.x & 63;
    int nRowWaves = nA / 8;
    float m0 = 1e30f, m1 = 1e30f, m2 = 1e30f, m3 = 1e30f;
    float m4 = 1e30f, m5 = 1e30f, m6 = 1e30f, m7 = 1e30f;
    if (gwave < nRowWaves) {
        int i0 = gwave * 8;
        float4 A0 = Apack[i0 + 0], A1 = Apack[i0 + 1], A2 = Apack[i0 + 2], A3 = Apack[i0 + 3];
        float4 A4 = Apack[i0 + 4], A5 = Apack[i0 + 5], A6 = Apack[i0 + 6], A7 = Apack[i0 + 7];
        for (int j = lane; j < nB; j += 64) {
            float4 b = Bpack[j];
            m0 = fminf(m0, d2_exact(A0.x, A0.y, A0.z, b.x, b.y, b.z));
            m1 = fminf(m1, d2_exact(A1.x, A1.y, A1.z, b.x, b.y, b.z));
            m2 = fminf(m2, d2_exact(A2.x, A2.y, A2.z, b.x, b.y, b.z));
            m3 = fminf(m3, d2_exact(A3.x, A3.y, A3.z, b.x, b.y, b.z));
            m4 = fminf(m4, d2_exact(A4.x, A4.y, A4.z, b.x, b.y, b.z));
            m5 = fminf(m5, d2_exact(A5.x, A5.y, A5.z, b.x, b.y, b.z));
            m6 = fminf(m6, d2_exact(A6.x, A6.y, A6.z, b.x, b.y, b.z));
            m7 = fminf(m7, d2_exact(A7.x, A7.y, A7.z, b.x, b.y, b.z));
        }
#pragma unroll
        for (int o = 32; o; o >>= 1) {
            m0 = fminf(m0, __shfl_xor(m0, o, 64)); m1 = fminf(m1, __shfl_xor(m1, o, 64));
            m2 = fminf(m2, __shfl_xor(m2, o, 64)); m3 = fminf(m3, __shfl_xor(m3, o, 64));
            m4 = fminf(m4, __shfl_xor(m4, o, 64)); m5 = fminf(m5, __shfl_xor(m5, o, 64));
            m6 = fminf(m6, __shfl_xor(m6, o, 64)); m7 = fminf(m7, __shfl_xor(m7, o, 64));
        }
        if (lane == 0) {
#define ROW_OUT(K, AK, MK)                                                         \
            {                                                                      \
                float Dm = f_D(MK);                                                \
                float hi = (AK.w > SAMPLE_THRESH) ? hi_thresh(MK) : -1e30f;        \
                rowpack[i0 + K] = make_float4(AK.x, AK.y, AK.z, hi);               \
                rowD[i0 + K] = Dm;                                                 \
            }
            ROW_OUT(0, A0, m0) ROW_OUT(1, A1, m1) ROW_OUT(2, A2, m2) ROW_OUT(3, A3, m3)
            ROW_OUT(4, A4, m4) ROW_OUT(5, A5, m5) ROW_OUT(6, A6, m6) ROW_OUT(7, A7, m7)
#undef ROW_OUT
        }
    } else {
        int j0 = (gwave - nRowWaves) * 8;
        if (j0 >= nB) return;
        float4 B0 = Bpack[j0 + 0], B1 = Bpack[j0 + 1], B2 = Bpack[j0 + 2], B3 = Bpack[j0 + 3];
        float4 B4 = Bpack[j0 + 4], B5 = Bpack[j0 + 5], B6 = Bpack[j0 + 6], B7 = Bpack[j0 + 7];
        for (int i = lane; i < nA; i += 64) {
            float4 a = Apack[i];
            m0 = fminf(m0, d2_exact(a.x, a.y, a.z, B0.x, B0.y, B0.z));
            m1 = fminf(m1, d2_exact(a.x, a.y, a.z, B1.x, B1.y, B1.z));
            m2 = fminf(m2, d2_exact(a.x, a.y, a.z, B2.x, B2.y, B2.z));
            m3 = fminf(m3, d2_exact(a.x, a.y, a.z, B3.x, B3.y, B3.z));
            m4 = fminf(m4, d2_exact(a.x, a.y, a.z, B4.x, B4.y, B4.z));
            m5 = fminf(m5, d2_exact(a.x, a.y, a.z, B5.x, B5.y, B5.z));
            m6 = fminf(m6, d2_exact(a.x, a.y, a.z, B6.x, B6.y, B6.z));
            m7 = fminf(m7, d2_exact(a.x, a.y, a.z, B7.x, B7.y, B7.z));
        }
#pragma unroll
        for (int o = 32; o; o >>= 1) {
            m0 = fminf(m0, __shfl_xor(m0, o, 64)); m1 = fminf(m1, __shfl_xor(m1, o, 64));
            m2 = fminf(m2, __shfl_xor(m2, o, 64)); m3 = fminf(m3, __shfl_xor(m3, o, 64));
            m4 = fminf(m4, __shfl_xor(m4, o, 64)); m5 = fminf(m5, __shfl_xor(m5, o, 64));
            m6 = fminf(m6, __shfl_xor(m6, o, 64)); m7 = fminf(m7, __shfl_xor(m7, o, 64));
        }
        if (lane == 0) {
#define COL_OUT(K, BK, MK)                                                         \
            colpack[j0 + K] = make_float4(BK.x, BK.y, BK.z, hi_thresh(MK));
            COL_OUT(0, B0, m0) COL_OUT(1, B1, m1) COL_OUT(2, B2, m2) COL_OUT(3, B3, m3)
            COL_OUT(4, B4, m4) COL_OUT(5, B5, m5) COL_OUT(6, B6, m6) COL_OUT(7, B7, m7)
#undef COL_OUT
        }
    }
}

// Kernel C: per 64x1024 tile, recompute d2 and test against the row/col hi
// thresholds (no sqrt needed); output value is DminRow where the mask fires.
// Write-bound: 256 MB, nontemporal float4 stores.
#define TI 64
#define TJ 1024
__global__ __launch_bounds__(256) void out_kernel(
    const float4* __restrict__ rowpack, const float* __restrict__ rowD,
    const float4* __restrict__ colpack, float* __restrict__ out, int N) {
    __shared__ float4 cp[TJ];
    __shared__ float4 rp[TI];
    __shared__ float rd[TI];
    int tid = threadIdx.x;
    int j0 = blockIdx.x * TJ;
    int i0 = blockIdx.y * TI;
    for (int k = tid; k < TJ; k += 256) cp[k] = colpack[j0 + k];
    if (tid < TI) { rp[tid] = rowpack[i0 + tid]; rd[tid] = rowD[i0 + tid]; }
    __syncthreads();
    float4 c0 = cp[tid * 4 + 0], c1 = cp[tid * 4 + 1];
    float4 c2 = cp[tid * 4 + 2], c3 = cp[tid * 4 + 3];
    size_t base = (size_t)i0 * (size_t)N + (size_t)j0 + (size_t)tid * 4;
#pragma unroll 2
    for (int r = 0; r < TI; ++r) {
        float4 a = rp[r];
        float Dm = rd[r];
        float d0 = d2_exact(a.x, a.y, a.z, c0.x, c0.y, c0.z);
        float d1 = d2_exact(a.x, a.y, a.z, c1.x, c1.y, c1.z);
        float d2 = d2_exact(a.x, a.y, a.z, c2.x, c2.y, c2.z);
        float d3 = d2_exact(a.x, a.y, a.z, c3.x, c3.y, c3.z);
        f32x4 o;
        o.x = (d0 <= a.w && d0 <= c0.w) ? Dm : 0.0f;
        o.y = (d1 <= a.w && d1 <= c1.w) ? Dm : 0.0f;
        o.z = (d2 <= a.w && d2 <= c2.w) ? Dm : 0.0f;
        o.w = (d3 <= a.w && d3 <= c3.w) ? Dm : 0.0f;
        __builtin_nontemporal_store(o, (f32x4*)(out + base + (size_t)r * (size_t)N));
    }
}

extern "C" void kernel_launch(void* const* d_in, const int* in_sizes, int n_in,
                              void* d_out, int out_size, void* d_ws, size_t ws_size,
                              hipStream_t stream) {
    const float* xA   = (const float*)d_in[0];
    const float* xB   = (const float*)d_in[1];
    const float* warp = (const float*)d_in[2];
    const float* cert = (const float*)d_in[3];
    int nA = in_sizes[0] / 2;   // 8192
    int nB = in_sizes[1] / 2;   // 8192
    const int H = 504, W = 1008;
    float* out = (float*)d_out;

    char* ws = (char*)d_ws;
    float4* Apack   = (float4*)ws;
    float4* Bpack   = Apack + nA;
    float4* rowpack = Bpack + nB;
    float4* colpack = rowpack + nA;
    float*  rowD    = (float*)(colpack + nB);

    int nmax = nA > nB ? nA : nB;
    sample_kernel<<<(nmax + 255) / 256, 256, 0, stream>>>(
        xA, xB, (const float4*)warp, cert, Apack, Bpack, nA, nB, H, W);

    int totWaves = nA / 8 + nB / 8;
    min_kernel<<<(totWaves * 64 + 255) / 256, 256, 0, stream>>>(
        Apack, Bpack, rowpack, rowD, colpack, nA, nB);

    dim3 grid(nB / TJ, nA / TI);
    out_kernel<<<grid, 256, 0, stream>>>(rowpack, rowD, colpack, out, nB);
}